// Round 3
// baseline (206.324 us; speedup 1.0000x reference)
//
#include <hip/hip_runtime.h>
#include <hip/hip_cooperative_groups.h>

namespace cg = cooperative_groups;

#define NGRAPH 128
#define NEDGE  131072
#define DIM    64
#define REPRW  192
#define NTHREADS 1024
#define LISTCAP 1024            // per-graph hit list capacity (expected ~64)
#define EPB (NEDGE / NGRAPH)    // 1024 edges per block slice, 1 per thread

// ---------------------------------------------------------------------------
// v4: single COOPERATIVE dispatch. v3's remaining scan cost was the O(B*E)
// redundancy: each of 128 blocks re-read the full 1 MB edge list from L2
// (16 MB/XCD ~ 3.7 us) and issued 16.7M hit tests. Here each block scans an
// exclusive E/128 slice once (one edge per thread), routes hits into
// per-graph workspace lists via global atomics, grid.sync()s, then replays
// its own ~64-entry list. Total edge traffic 1 MB, 131K tests. No extra
// dispatch (v2 showed ~2.5 us per-dispatch overhead).
//
// Mode routing (reproduces io-m6, oo-m5, ii-m5, oi-m6, m5, m6; self-loops on
// head/tail correctly produce two events):
//   d==gb   : mode 5 if s==gb+1 else mode 0
//   d==gb+1 : skip if s==gb (m5 counted on src side) else mode 2
//   s==gb   : mode 4 if d==gb+1 else mode 1
//   s==gb+1 : skip if d==gb (m6 counted on dst side) else mode 3
//
// Workspace: [0,512): int gcnt[128]; [512, 512+512K): int glist[128][1024].
// gcnt zeroed in-kernel before grid sync #1 (workspace is poisoned between
// iterations; no state survives — idempotent).
// ---------------------------------------------------------------------------
__global__ __launch_bounds__(NTHREADS) void fused_graph_kernel(
    const float* __restrict__ node_repr, const float* __restrict__ rel_emb,
    const float* __restrict__ W_reld, const float* __restrict__ b_reld,
    const float* __restrict__ Wc, const float* __restrict__ bc,
    const float* __restrict__ Wf, const float* __restrict__ bf,
    const int* __restrict__ esrc, const int* __restrict__ edst,
    const int* __restrict__ etype, const int* __restrict__ rel_labels,
    const int* __restrict__ head_ids, const int* __restrict__ tail_ids,
    int* __restrict__ gcnt, int* __restrict__ glist,
    float* __restrict__ out)
{
    const int b    = blockIdx.x;
    const int tid  = threadIdx.x;
    const int base = b << 6;
    const int wave = tid >> 6;
    const int lane = tid & 63;

    __shared__ __align__(16) float shS[6 * 64];
    __shared__ float shCnt[6];
    __shared__ float sh_grep[640];   // [g_out(192)|head(192)|tail(192)|rel_final(64)]
    __shared__ float sh_part[4 * 192];
    __shared__ float sh_v[6 * 64];
    __shared__ float sh_rn[64];
    __shared__ float sh_Wc[64 * 129];  // Wc padded: lane f row at f*129 (2 lanes/bank = free)
    __shared__ float sh_red[16];

    // --- init: LDS accumulators + own global counter (device-scope atomic) ---
    if (tid < 384) shS[tid] = 0.0f;
    if (tid < 6)   shCnt[tid] = 0.0f;
    if (tid == 0)  atomicExch(&gcnt[b], 0);

    // --- phase 1a: node_repr slab mean partials + head/tail staging ---
    {
        int r = tid / 192, col = tid - r * 192;
        if (tid < 768) {
            const float* p = node_repr + (size_t)(base + r * 16) * REPRW + col;
            float a = 0.0f;
            #pragma unroll
            for (int n = 0; n < 16; n++) a += p[(size_t)n * REPRW];
            sh_part[r * 192 + col] = a;
        }
        if (tid < 192) {
            sh_grep[192 + tid] = node_repr[(size_t)head_ids[b] * REPRW + tid];
            sh_grep[384 + tid] = node_repr[(size_t)tail_ids[b] * REPRW + tid];
        }
    }

    cg::this_grid().sync();   // all gcnt zeroed

    // --- phase 1b: scan exclusive slice, scatter routed hits to glist ---
    {
        const int e = b * EPB + tid;
        const int s = esrc[e];
        const int d = edst[e];
        const bool hd = (d & 63) < 2;
        const bool hs = (s & 63) < 2;
        if (hd | hs) {
            const int et = etype[e];                 // load only on hit (~6%)
            if (hd) {
                const int g = d >> 6, gb = g << 6;
                int m = (d == gb) ? ((s == gb + 1) ? 5 : 0)
                                  : ((s == gb) ? -1 : 2);
                if (m >= 0) {
                    int slot = atomicAdd(&gcnt[g], 1);
                    if (slot < LISTCAP) glist[g * LISTCAP + slot] = (m << 8) | et;
                }
            }
            if (hs) {
                const int g = s >> 6, gb = g << 6;
                int m = (s == gb) ? ((d == gb + 1) ? 4 : 1)
                                  : ((d == gb) ? -1 : 3);
                if (m >= 0) {
                    int slot = atomicAdd(&gcnt[g], 1);
                    if (slot < LISTCAP) glist[g * LISTCAP + slot] = (m << 8) | et;
                }
            }
        }
    }
    __threadfence();          // glist plain stores visible device-wide
    cg::this_grid().sync();   // all scatters complete

    // --- phase 2: replay own hit list (16 waves) + g_out combine ---
    {
        int nh = gcnt[b];
        if (nh > LISTCAP) nh = LISTCAP;
        const int* mylist = glist + b * LISTCAP;
        for (int h = wave; h < nh; h += 16) {
            int ent = mylist[h];
            int m = ent >> 8, t = ent & 0xff;
            atomicAdd(&shS[m * 64 + lane], rel_emb[t * 64 + lane]);
            if (lane == 0) atomicAdd(&shCnt[m], 1.0f);
        }
        if (tid < 192)
            sh_grep[tid] = (sh_part[tid] + sh_part[192 + tid] +
                            sh_part[384 + tid] + sh_part[576 + tid]) * (1.0f / 64.0f);
    }
    __syncthreads();

    // --- phase 3: per-(mode,f) GEMV + Wc staging ---
    if (tid < 384) {
        int m = wave, f = lane;   // waves 0..5, wave-uniform m
        const float4* Wrow = (const float4*)(W_reld + (m * 64 + f) * 64);
        const float4* Sv   = (const float4*)(shS + m * 64);
        float dot = 0.0f;
        #pragma unroll
        for (int k = 0; k < 16; k++) {
            float4 w = Wrow[k];
            float4 sv = Sv[k];     // wave-uniform address -> broadcast, no conflict
            dot += w.x * sv.x + w.y * sv.y + w.z * sv.z + w.w * sv.w;
        }
        float cm = shCnt[m];
        sh_v[m * 64 + f] = (dot + cm * b_reld[m * 64 + f]) / (cm + 1e-30f);
    } else {
        for (int j = tid - 384; j < 64 * 128; j += NTHREADS - 384) {
            int row = j >> 7, col = j & 127;
            sh_Wc[row * 129 + col] = Wc[j];
        }
    }
    __syncthreads();

    // --- phase 4: rel_neighbor = mean over modes ---
    if (tid < 64) {
        sh_rn[tid] = (sh_v[tid] + sh_v[64 + tid] + sh_v[128 + tid] +
                      sh_v[192 + tid] + sh_v[256 + tid] + sh_v[320 + tid]) * (1.0f / 6.0f);
    }
    __syncthreads();

    // --- phase 5: rel_final (one wave; shuffles safe) ---
    if (tid < 64) {
        const float* rl = rel_emb + rel_labels[b] * DIM;
        const float* Wrow = sh_Wc + tid * 129;
        float z = bc[tid];
        #pragma unroll 8
        for (int j = 0; j < 64; j++) z += sh_rn[j] * Wrow[j];
        #pragma unroll 8
        for (int j = 0; j < 64; j++) z += rl[j] * Wrow[64 + j];
        z = fmaxf(z, 0.0f);
        float sq = z * z;
        #pragma unroll
        for (int off = 32; off >= 1; off >>= 1) sq += __shfl_xor(sq, off);
        float nrm = fmaxf(sqrtf(sq), 1e-12f);
        sh_grep[576 + tid] = z / nrm;
    }
    __syncthreads();

    // --- phase 6: final 640-dot with Wf (10 full waves) ---
    if (tid < 640) {
        float p = sh_grep[tid] * Wf[tid];
        #pragma unroll
        for (int off = 32; off >= 1; off >>= 1) p += __shfl_xor(p, off);
        if (lane == 0) sh_red[wave] = p;
    }
    __syncthreads();
    if (tid == 0) {
        float acc = bf[0];
        #pragma unroll
        for (int w = 0; w < 10; w++) acc += sh_red[w];
        out[b] = acc;
    }
}

extern "C" void kernel_launch(void* const* d_in, const int* in_sizes, int n_in,
                              void* d_out, int out_size, void* d_ws, size_t ws_size,
                              hipStream_t stream) {
    (void)in_sizes; (void)n_in; (void)out_size; (void)ws_size;

    const float* node_repr = (const float*)d_in[0];
    const float* rel_emb   = (const float*)d_in[1];
    const float* W_reld    = (const float*)d_in[2];
    const float* b_reld    = (const float*)d_in[3];
    const float* Wc        = (const float*)d_in[4];
    const float* bc        = (const float*)d_in[5];
    const float* Wf        = (const float*)d_in[6];
    const float* bf        = (const float*)d_in[7];
    const int*   esrc      = (const int*)d_in[8];
    const int*   edst      = (const int*)d_in[9];
    const int*   etype     = (const int*)d_in[10];
    const int*   rel_labels= (const int*)d_in[11];
    // d_in[12] node_graph_id: structurally arange(N)//64, unused
    const int*   head_ids  = (const int*)d_in[13];
    const int*   tail_ids  = (const int*)d_in[14];

    int* gcnt  = (int*)d_ws;
    int* glist = (int*)((char*)d_ws + 512);
    float* outp = (float*)d_out;

    void* args[] = {
        (void*)&node_repr, (void*)&rel_emb, (void*)&W_reld, (void*)&b_reld,
        (void*)&Wc, (void*)&bc, (void*)&Wf, (void*)&bf,
        (void*)&esrc, (void*)&edst, (void*)&etype, (void*)&rel_labels,
        (void*)&head_ids, (void*)&tail_ids,
        (void*)&gcnt, (void*)&glist, (void*)&outp
    };
    hipLaunchCooperativeKernel((const void*)fused_graph_kernel,
                               dim3(NGRAPH), dim3(NTHREADS), args, 0, stream);
}

// Round 4
// 106.709 us; speedup vs baseline: 1.9335x; 1.9335x over previous
//
#include <hip/hip_runtime.h>

#define NGRAPH 128
#define NEDGE  131072
#define DIM    64
#define REPRW  192
#define NTHREADS 1024
#define MAXHITS 1024

// ---------------------------------------------------------------------------
// v5 = v3 (best verified: 110.6 us) + scan micro-opts. Lessons encoded:
//  - v2: extra dispatches cost ~2.5-4 us each -> single fused dispatch.
//  - v4: cooperative grid.sync costs ~40 us/sync on this stack -> no
//    cross-block coordination; per-block redundant scan is cheaper.
//  - v0->v3: thin hit body (append edge id only) saves ~2.5 us; mode
//    routing done in the ~64-entry replay phase.
// Scan micro-opts here: umin-based hit test (4 VALU/edge) and 8-edge
// groups (2x int4 per array per iter, 16 iters/thread) to halve loop
// overhead.
//
// One block per graph b (1024 threads = 16 waves). Phases:
//  1a. 768 thr: 64-node mean partials of this graph's node_repr slab;
//      192 thr stage head/tail rows.
//  1b. all threads scan all E edges (L2-broadcast across blocks); hit
//      body = append edge id to LDS list (atomicAdd + ds_write).
//  2.  16 waves replay the ~64-entry list: load s/d/etype (wave-uniform,
//      L2), route modes, LDS-atomicAdd rel_emb row into S[6][64] + shCnt.
//      Mode routing (io-m6, oo-m5, ii-m5, oi-m6, m5, m6; self-loops on
//      head/tail correctly produce two events):
//        d==base   : mode 5 if s==base+1 else mode 0
//        d==base+1 : skip if s==base (m5 counted on src side) else mode 2
//        s==base   : mode 4 if d==base+1 else mode 1
//        s==base+1 : skip if d==base (m6 counted on dst side) else mode 3
//  3.  384 thr: v[m][f] = (W_reld[m,f,:]·S[m] + cnt_m·b_reld[m,f])/(cnt_m+eps)
//      640 thr: stage Wc into LDS padded to 129 floats/row (conflict-free).
//  4.  rel_neighbor mean over modes
//  5.  rel_final = l2norm(relu([rn, rel_emb[label]] @ Wc.T + bc))  (1 wave)
//  6.  out[b] = [g_out | head | tail | rel_final] · Wf + bf        (10 waves)
// ---------------------------------------------------------------------------
__global__ __launch_bounds__(NTHREADS) void fused_graph_kernel(
    const float* __restrict__ node_repr, const float* __restrict__ rel_emb,
    const float* __restrict__ W_reld, const float* __restrict__ b_reld,
    const float* __restrict__ Wc, const float* __restrict__ bc,
    const float* __restrict__ Wf, const float* __restrict__ bf,
    const int* __restrict__ esrc, const int* __restrict__ edst,
    const int* __restrict__ etype, const int* __restrict__ rel_labels,
    const int* __restrict__ head_ids, const int* __restrict__ tail_ids,
    float* __restrict__ out)
{
    const int b    = blockIdx.x;
    const int tid  = threadIdx.x;
    const int base = b << 6;
    const int wave = tid >> 6;
    const int lane = tid & 63;

    __shared__ __align__(16) float shS[6 * 64];
    __shared__ float shCnt[6];
    __shared__ int   shList[MAXHITS];
    __shared__ int   shNHits;
    __shared__ float sh_grep[640];   // [g_out(192)|head(192)|tail(192)|rel_final(64)]
    __shared__ float sh_part[4 * 192];
    __shared__ float sh_v[6 * 64];
    __shared__ float sh_rn[64];
    __shared__ float sh_Wc[64 * 129];  // Wc padded: lane f row at f*129 (2 lanes/bank = free)
    __shared__ float sh_red[16];

    // --- init LDS accumulators ---
    if (tid < 384) shS[tid] = 0.0f;
    if (tid < 6)   shCnt[tid] = 0.0f;
    if (tid == 0)  shNHits = 0;
    __syncthreads();

    // --- phase 1a: node_repr slab mean partials + head/tail staging ---
    {
        int r = tid / 192, col = tid - r * 192;
        if (tid < 768) {
            const float* p = node_repr + (size_t)(base + r * 16) * REPRW + col;
            float a = 0.0f;
            #pragma unroll
            for (int n = 0; n < 16; n++) a += p[(size_t)n * REPRW];
            sh_part[r * 192 + col] = a;
        }
        if (tid < 192) {
            sh_grep[192 + tid] = node_repr[(size_t)head_ids[b] * REPRW + tid];
            sh_grep[384 + tid] = node_repr[(size_t)tail_ids[b] * REPRW + tid];
        }
    }

    // --- phase 1b: edge scan, 8 edges/iter, minimal hit body ---
    {
        const int4* s4 = (const int4*)esrc;
        const int4* d4 = (const int4*)edst;
        for (int i = tid; i < NEDGE / 8; i += NTHREADS) {   // 16 iterations
            int4 ss0 = s4[2 * i],     dd0 = d4[2 * i];
            int4 ss1 = s4[2 * i + 1], dd1 = d4[2 * i + 1];
            int sv[8] = {ss0.x, ss0.y, ss0.z, ss0.w, ss1.x, ss1.y, ss1.z, ss1.w};
            int dv[8] = {dd0.x, dd0.y, dd0.z, dd0.w, dd1.x, dd1.y, dd1.z, dd1.w};
            #pragma unroll
            for (int c = 0; c < 8; c++) {
                unsigned su = (unsigned)(sv[c] - base);
                unsigned du = (unsigned)(dv[c] - base);
                if (min(su, du) < 2u) {
                    int idx = atomicAdd(&shNHits, 1);
                    if (idx < MAXHITS) shList[idx] = 8 * i + c;
                }
            }
        }
    }
    __syncthreads();

    // --- phase 2: replay hit list (mode routing here, ~64 entries) ---
    {
        int nh = shNHits < MAXHITS ? shNHits : MAXHITS;
        for (int h = wave; h < nh; h += 16) {
            int e = shList[h];
            unsigned dl = (unsigned)(edst[e] - base);
            unsigned sl = (unsigned)(esrc[e] - base);
            int t = etype[e];
            float rv = rel_emb[t * 64 + lane];      // coalesced row, reused below
            if (dl < 2u) {
                int m = (dl == 0u) ? ((sl == 1u) ? 5 : 0)
                                   : ((sl == 0u) ? -1 : 2);
                if (m >= 0) {
                    atomicAdd(&shS[m * 64 + lane], rv);
                    if (lane == 0) atomicAdd(&shCnt[m], 1.0f);
                }
            }
            if (sl < 2u) {
                int m = (sl == 0u) ? ((dl == 1u) ? 4 : 1)
                                   : ((dl == 0u) ? -1 : 3);
                if (m >= 0) {
                    atomicAdd(&shS[m * 64 + lane], rv);
                    if (lane == 0) atomicAdd(&shCnt[m], 1.0f);
                }
            }
        }
        if (tid < 192)
            sh_grep[tid] = (sh_part[tid] + sh_part[192 + tid] +
                            sh_part[384 + tid] + sh_part[576 + tid]) * (1.0f / 64.0f);
    }
    __syncthreads();

    // --- phase 3: per-(mode,f) GEMV + Wc staging ---
    if (tid < 384) {
        int m = wave, f = lane;   // waves 0..5, wave-uniform m
        const float4* Wrow = (const float4*)(W_reld + (m * 64 + f) * 64);
        const float4* Sv   = (const float4*)(shS + m * 64);
        float dot = 0.0f;
        #pragma unroll
        for (int k = 0; k < 16; k++) {
            float4 w = Wrow[k];
            float4 sv = Sv[k];     // wave-uniform address -> broadcast, no conflict
            dot += w.x * sv.x + w.y * sv.y + w.z * sv.z + w.w * sv.w;
        }
        float cm = shCnt[m];
        sh_v[m * 64 + f] = (dot + cm * b_reld[m * 64 + f]) / (cm + 1e-30f);
    } else {
        for (int j = tid - 384; j < 64 * 128; j += NTHREADS - 384) {
            int row = j >> 7, col = j & 127;
            sh_Wc[row * 129 + col] = Wc[j];
        }
    }
    __syncthreads();

    // --- phase 4: rel_neighbor = mean over modes ---
    if (tid < 64) {
        sh_rn[tid] = (sh_v[tid] + sh_v[64 + tid] + sh_v[128 + tid] +
                      sh_v[192 + tid] + sh_v[256 + tid] + sh_v[320 + tid]) * (1.0f / 6.0f);
    }
    __syncthreads();

    // --- phase 5: rel_final (one wave; shuffles safe) ---
    if (tid < 64) {
        const float* rl = rel_emb + rel_labels[b] * DIM;
        const float* Wrow = sh_Wc + tid * 129;
        float z = bc[tid];
        #pragma unroll 8
        for (int j = 0; j < 64; j++) z += sh_rn[j] * Wrow[j];
        #pragma unroll 8
        for (int j = 0; j < 64; j++) z += rl[j] * Wrow[64 + j];
        z = fmaxf(z, 0.0f);
        float sq = z * z;
        #pragma unroll
        for (int off = 32; off >= 1; off >>= 1) sq += __shfl_xor(sq, off);
        float nrm = fmaxf(sqrtf(sq), 1e-12f);
        sh_grep[576 + tid] = z / nrm;
    }
    __syncthreads();

    // --- phase 6: final 640-dot with Wf (10 full waves) ---
    if (tid < 640) {
        float p = sh_grep[tid] * Wf[tid];
        #pragma unroll
        for (int off = 32; off >= 1; off >>= 1) p += __shfl_xor(p, off);
        if (lane == 0) sh_red[wave] = p;
    }
    __syncthreads();
    if (tid == 0) {
        float acc = bf[0];
        #pragma unroll
        for (int w = 0; w < 10; w++) acc += sh_red[w];
        out[b] = acc;
    }
}

extern "C" void kernel_launch(void* const* d_in, const int* in_sizes, int n_in,
                              void* d_out, int out_size, void* d_ws, size_t ws_size,
                              hipStream_t stream) {
    (void)in_sizes; (void)n_in; (void)out_size; (void)d_ws; (void)ws_size;

    const float* node_repr = (const float*)d_in[0];
    const float* rel_emb   = (const float*)d_in[1];
    const float* W_reld    = (const float*)d_in[2];
    const float* b_reld    = (const float*)d_in[3];
    const float* Wc        = (const float*)d_in[4];
    const float* bc        = (const float*)d_in[5];
    const float* Wf        = (const float*)d_in[6];
    const float* bf        = (const float*)d_in[7];
    const int*   esrc      = (const int*)d_in[8];
    const int*   edst      = (const int*)d_in[9];
    const int*   etype     = (const int*)d_in[10];
    const int*   rel_labels= (const int*)d_in[11];
    // d_in[12] node_graph_id: structurally arange(N)//64, unused
    const int*   head_ids  = (const int*)d_in[13];
    const int*   tail_ids  = (const int*)d_in[14];

    fused_graph_kernel<<<NGRAPH, NTHREADS, 0, stream>>>(
        node_repr, rel_emb, W_reld, b_reld, Wc, bc, Wf, bf,
        esrc, edst, etype, rel_labels, head_ids, tail_ids, (float*)d_out);
}